// Round 2
// baseline (743.623 us; speedup 1.0000x reference)
//
#include <hip/hip_runtime.h>

// Problem constants (B=8, S=200, H=4, D=64, HID=256) — all tensors fp32.
#define SB 8
#define SS 200
#define HID 256
#define NH 4
#define DH 64

// ---------------------------------------------------------------------------
// Kernel A: q = in@Wq+bq ; k = in@Wk+bk ; kpk = k+posK ; vpv = in@Wv+bv+posV
// grid (100, 3), block 256. 16 rows per block, 4x4 register tile per thread.
// ---------------------------------------------------------------------------
__global__ __launch_bounds__(256) void proj_kernel(
    const float* __restrict__ in,
    const float* __restrict__ Wq, const float* __restrict__ bq,
    const float* __restrict__ Wk, const float* __restrict__ bk,
    const float* __restrict__ Wv, const float* __restrict__ bv,
    const float* __restrict__ posK, const float* __restrict__ posV,
    float* __restrict__ q_out, float* __restrict__ k_out,
    float* __restrict__ kpk_out, float* __restrict__ vpv_out)
{
    const int which = blockIdx.y;
    const float* W = (which == 0) ? Wq : (which == 1) ? Wk : Wv;
    const float* bias = (which == 0) ? bq : (which == 1) ? bk : bv;
    const int row0 = blockIdx.x * 16;
    __shared__ float sin_[16][HID];
    const int t = threadIdx.x;
    for (int r = 0; r < 16; r++)
        sin_[r][t] = in[(size_t)(row0 + r) * HID + t];
    __syncthreads();
    const int tx = t & 63, ty = t >> 6;
    const int c0 = tx * 4, r0 = ty * 4;
    float acc[4][4] = {};
    for (int kk = 0; kk < HID; kk++) {
        const float4 wv4 = *(const float4*)(W + (size_t)kk * HID + c0);
        float a[4];
        #pragma unroll
        for (int r = 0; r < 4; r++) a[r] = sin_[r0 + r][kk];
        #pragma unroll
        for (int r = 0; r < 4; r++) {
            acc[r][0] += a[r] * wv4.x;
            acc[r][1] += a[r] * wv4.y;
            acc[r][2] += a[r] * wv4.z;
            acc[r][3] += a[r] * wv4.w;
        }
    }
    const float4 b4 = *(const float4*)(bias + c0);
    #pragma unroll
    for (int r = 0; r < 4; r++) {
        const size_t off = (size_t)(row0 + r0 + r) * HID + c0;
        float4 o;
        o.x = acc[r][0] + b4.x;
        o.y = acc[r][1] + b4.y;
        o.z = acc[r][2] + b4.z;
        o.w = acc[r][3] + b4.w;
        if (which == 0) {
            *(float4*)(q_out + off) = o;
        } else if (which == 1) {
            *(float4*)(k_out + off) = o;
            const float4 p4 = *(const float4*)(posK + off);
            float4 s;
            s.x = o.x + p4.x; s.y = o.y + p4.y;
            s.z = o.z + p4.z; s.w = o.w + p4.w;
            *(float4*)(kpk_out + off) = s;
        } else {
            const float4 p4 = *(const float4*)(posV + off);
            float4 s;
            s.x = o.x + p4.x; s.y = o.y + p4.y;
            s.z = o.z + p4.z; s.w = o.w + p4.w;
            *(float4*)(vpv_out + off) = s;
        }
    }
}

// ---------------------------------------------------------------------------
// Kernel A2: per-(row,head) scalars qo = q_h.order_w[:64], ko = k_h.order_w[64:],
// qd = q_h.dist_w[:64], kd = k_h.dist_w[64:].  grid 1600, block 64.
// ---------------------------------------------------------------------------
__global__ __launch_bounds__(64) void rowdots_kernel(
    const float* __restrict__ q, const float* __restrict__ k,
    const float* __restrict__ order_w, const float* __restrict__ dist_w,
    float* __restrict__ qo, float* __restrict__ ko,
    float* __restrict__ qd, float* __restrict__ kd)
{
    const int row = blockIdx.x;
    const int l = threadIdx.x;
    const float ow1 = order_w[l], ow2 = order_w[64 + l];
    const float dw1 = dist_w[l],  dw2 = dist_w[64 + l];
    for (int h = 0; h < NH; h++) {
        const float qe = q[(size_t)row * HID + h * DH + l];
        const float ke = k[(size_t)row * HID + h * DH + l];
        float a = qe * ow1, b = ke * ow2, c = qe * dw1, d = ke * dw2;
        #pragma unroll
        for (int m = 32; m >= 1; m >>= 1) {
            a += __shfl_xor(a, m, 64);
            b += __shfl_xor(b, m, 64);
            c += __shfl_xor(c, m, 64);
            d += __shfl_xor(d, m, 64);
        }
        if (l == 0) {
            qo[row * NH + h] = a;
            ko[row * NH + h] = b;
            qd[row * NH + h] = c;
            kd[row * NH + h] = d;
        }
    }
}

// ---------------------------------------------------------------------------
// Kernel B: HBM-bound attention. One block per (b,i), 256 threads = 4 waves.
// One wave per j-row (64 lanes x float4 = 1 KB = 256 floats); head = l>>4.
// Pass 1: scores[h][j] = (q.(kpk_j + timeK_ij) + err_order + err_dist)/8 + mask
// Softmax per head (wave w handles head w).
// Pass 2: ctx = sum_j p_hj * (vpv_j + timeV_ij).
// ---------------------------------------------------------------------------
__global__ __launch_bounds__(256) void attn_kernel(
    const float* __restrict__ q, const float* __restrict__ kpk,
    const float* __restrict__ vpv,
    const float* __restrict__ timeK, const float* __restrict__ timeV,
    const float* __restrict__ mask,
    const float* __restrict__ qo, const float* __restrict__ ko,
    const float* __restrict__ qd, const float* __restrict__ kd,
    const float* __restrict__ order_b_p, const float* __restrict__ dist_b_p,
    const float* __restrict__ scalar_p,
    float* __restrict__ ctx)
{
    const int blk = blockIdx.x;
    const int b = blk / SS, i = blk - b * SS;
    const int t = threadIdx.x;
    const int w = t >> 6, l = t & 63;
    const int h = l >> 4;           // head handled by this lane
    const int sub = l & 15;         // 16 lanes per head

    __shared__ float sh_q[HID];
    __shared__ float sh_s[NH][SS + 8];
    __shared__ float sh_red[4][HID];

    const size_t rowq = (size_t)blk * HID;
    sh_q[t] = q[rowq + t];
    __syncthreads();

    const int d0 = l * 4;           // element range [d0, d0+4) == head h dims
    const float4 qr = *(const float4*)(sh_q + d0);

    const float qo_h = qo[blk * NH + h];
    const float qd_h = qd[blk * NH + h];
    const float order_b = *order_b_p;
    const float dist_b = *dist_b_p;
    const float sc = *scalar_p;
    const float sc2h = 0.5f * sc * sc;
    const size_t tb = (size_t)blk * SS;   // row base into [B*S, S] tables

    // ---- Pass 1: scores ----
    for (int j0 = 0; j0 < SS; j0 += 4) {
        const int j = j0 + w;
        const float4 tk = *(const float4*)(timeK + (tb + j) * (size_t)HID + d0);
        const float4 kk = *(const float4*)(kpk + ((size_t)(b * SS + j)) * HID + d0);
        float part = (tk.x + kk.x) * qr.x + (tk.y + kk.y) * qr.y
                   + (tk.z + kk.z) * qr.z + (tk.w + kk.w) * qr.w;
        part += __shfl_xor(part, 1, 64);
        part += __shfl_xor(part, 2, 64);
        part += __shfl_xor(part, 4, 64);
        part += __shfl_xor(part, 8, 64);
        if (sub == 0) {
            const float ko_jh = ko[(b * SS + j) * NH + h];
            const float kd_jh = kd[(b * SS + j) * NH + h];
            const float xo = qo_h + ko_jh + order_b;
            const float pr = 1.0f / (1.0f + __expf(-xo));
            const float eo = (j > i) ? __logf(pr + 1e-24f) : __logf(1.0f - pr + 1e-24f);
            const float xd = qd_h + kd_jh + dist_b;
            const float gd = __logf(fabsf((float)(i - j)) + 1.0f);
            const float dd = gd - xd;
            const float ed = -dd * dd * sc2h;
            const float mk = mask[tb + j];
            sh_s[h][j] = (part + eo + ed) * 0.125f + mk;
        }
    }
    __syncthreads();

    // ---- Softmax: wave w handles head w ----
    {
        float vals[4];
        float m = -1e30f;
        #pragma unroll
        for (int rep = 0; rep < 4; rep++) {
            const int j = l + rep * 64;
            vals[rep] = (j < SS) ? sh_s[w][j] : -1e30f;
            m = fmaxf(m, vals[rep]);
        }
        #pragma unroll
        for (int mm = 32; mm >= 1; mm >>= 1) m = fmaxf(m, __shfl_xor(m, mm, 64));
        float sum = 0.0f;
        float es[4];
        #pragma unroll
        for (int rep = 0; rep < 4; rep++) {
            const int j = l + rep * 64;
            if (j < SS) { es[rep] = __expf(vals[rep] - m); sum += es[rep]; }
        }
        #pragma unroll
        for (int mm = 32; mm >= 1; mm >>= 1) sum += __shfl_xor(sum, mm, 64);
        const float inv = 1.0f / sum;
        #pragma unroll
        for (int rep = 0; rep < 4; rep++) {
            const int j = l + rep * 64;
            if (j < SS) sh_s[w][j] = es[rep] * inv;
        }
    }
    __syncthreads();

    // ---- Pass 2: context ----
    float4 acc = make_float4(0.f, 0.f, 0.f, 0.f);
    for (int j0 = 0; j0 < SS; j0 += 4) {
        const int j = j0 + w;
        const float4 tv = *(const float4*)(timeV + (tb + j) * (size_t)HID + d0);
        const float4 vv = *(const float4*)(vpv + ((size_t)(b * SS + j)) * HID + d0);
        const float p = sh_s[h][j];
        acc.x += p * (tv.x + vv.x);
        acc.y += p * (tv.y + vv.y);
        acc.z += p * (tv.z + vv.z);
        acc.w += p * (tv.w + vv.w);
    }
    *(float4*)(&sh_red[w][d0]) = acc;
    __syncthreads();
    ctx[rowq + t] = sh_red[0][t] + sh_red[1][t] + sh_red[2][t] + sh_red[3][t];
}

// ---------------------------------------------------------------------------
// Kernel C: hs = ctx@Wd + bd + input (residual). grid 100, block 256.
// ---------------------------------------------------------------------------
__global__ __launch_bounds__(256) void outproj_kernel(
    const float* __restrict__ ctx, const float* __restrict__ Wd,
    const float* __restrict__ bd, const float* __restrict__ input,
    float* __restrict__ hs)
{
    const int row0 = blockIdx.x * 16;
    __shared__ float sin_[16][HID];
    const int t = threadIdx.x;
    for (int r = 0; r < 16; r++)
        sin_[r][t] = ctx[(size_t)(row0 + r) * HID + t];
    __syncthreads();
    const int tx = t & 63, ty = t >> 6;
    const int c0 = tx * 4, r0 = ty * 4;
    float acc[4][4] = {};
    for (int kk = 0; kk < HID; kk++) {
        const float4 wv4 = *(const float4*)(Wd + (size_t)kk * HID + c0);
        float a[4];
        #pragma unroll
        for (int r = 0; r < 4; r++) a[r] = sin_[r0 + r][kk];
        #pragma unroll
        for (int r = 0; r < 4; r++) {
            acc[r][0] += a[r] * wv4.x;
            acc[r][1] += a[r] * wv4.y;
            acc[r][2] += a[r] * wv4.z;
            acc[r][3] += a[r] * wv4.w;
        }
    }
    const float4 b4 = *(const float4*)(bd + c0);
    #pragma unroll
    for (int r = 0; r < 4; r++) {
        const size_t off = (size_t)(row0 + r0 + r) * HID + c0;
        const float4 i4 = *(const float4*)(input + off);
        float4 o;
        o.x = acc[r][0] + b4.x + i4.x;
        o.y = acc[r][1] + b4.y + i4.y;
        o.z = acc[r][2] + b4.z + i4.z;
        o.w = acc[r][3] + b4.w + i4.w;
        *(float4*)(hs + off) = o;
    }
}

// ---------------------------------------------------------------------------
// Kernel D: LayerNorm over last dim (256). grid 1600, block 256. fp32 out.
// ---------------------------------------------------------------------------
__global__ __launch_bounds__(256) void ln_kernel(
    const float* __restrict__ hs, const float* __restrict__ g,
    const float* __restrict__ be, float* __restrict__ out)
{
    const int row = blockIdx.x;
    const int t = threadIdx.x;
    const int w = t >> 6, l = t & 63;
    __shared__ float red[4];
    const float v = hs[(size_t)row * HID + t];
    float s = v;
    #pragma unroll
    for (int m = 32; m >= 1; m >>= 1) s += __shfl_xor(s, m, 64);
    if (l == 0) red[w] = s;
    __syncthreads();
    const float mu = (red[0] + red[1] + red[2] + red[3]) * (1.0f / 256.0f);
    __syncthreads();
    const float d = v - mu;
    float s2 = d * d;
    #pragma unroll
    for (int m = 32; m >= 1; m >>= 1) s2 += __shfl_xor(s2, m, 64);
    if (l == 0) red[w] = s2;
    __syncthreads();
    const float var = (red[0] + red[1] + red[2] + red[3]) * (1.0f / 256.0f);
    out[(size_t)row * HID + t] = d * rsqrtf(var + 1e-12f) * g[t] + be[t];
}

// ---------------------------------------------------------------------------
extern "C" void kernel_launch(void* const* d_in, const int* in_sizes, int n_in,
                              void* d_out, int out_size, void* d_ws, size_t ws_size,
                              hipStream_t stream) {
    const float* input   = (const float*)d_in[0];
    const float* mask    = (const float*)d_in[1];
    const float* posK    = (const float*)d_in[2];
    const float* posV    = (const float*)d_in[3];
    const float* timeK   = (const float*)d_in[4];
    const float* timeV   = (const float*)d_in[5];
    const float* Wq      = (const float*)d_in[6];
    const float* bq      = (const float*)d_in[7];
    const float* Wk      = (const float*)d_in[8];
    const float* bk      = (const float*)d_in[9];
    const float* Wv      = (const float*)d_in[10];
    const float* bv      = (const float*)d_in[11];
    const float* order_w = (const float*)d_in[12];
    const float* order_b = (const float*)d_in[13];
    const float* dist_w  = (const float*)d_in[14];
    const float* dist_b  = (const float*)d_in[15];
    const float* scalar  = (const float*)d_in[16];
    const float* Wd      = (const float*)d_in[17];
    const float* bd      = (const float*)d_in[18];
    const float* ln_g    = (const float*)d_in[19];
    const float* ln_b    = (const float*)d_in[20];

    const int NROW = SB * SS;          // 1600
    float* ws = (float*)d_ws;
    float* q_ws   = ws;                 // 409600
    float* k_ws   = q_ws   + 409600;
    float* kpk_ws = k_ws   + 409600;
    float* vpv_ws = kpk_ws + 409600;
    float* qo_ws  = vpv_ws + 409600;    // 6400
    float* ko_ws  = qo_ws  + 6400;
    float* qd_ws  = ko_ws  + 6400;
    float* kd_ws  = qd_ws  + 6400;
    float* ctx_ws = kd_ws  + 6400;      // 409600
    float* hs_ws  = ctx_ws + 409600;    // 409600  (~9.9 MB total)

    proj_kernel<<<dim3(NROW / 16, 3), 256, 0, stream>>>(
        input, Wq, bq, Wk, bk, Wv, bv, posK, posV,
        q_ws, k_ws, kpk_ws, vpv_ws);
    rowdots_kernel<<<NROW, 64, 0, stream>>>(
        q_ws, k_ws, order_w, dist_w, qo_ws, ko_ws, qd_ws, kd_ws);
    attn_kernel<<<NROW, 256, 0, stream>>>(
        q_ws, kpk_ws, vpv_ws, timeK, timeV, mask,
        qo_ws, ko_ws, qd_ws, kd_ws, order_b, dist_b, scalar, ctx_ws);
    outproj_kernel<<<NROW / 16, 256, 0, stream>>>(
        ctx_ws, Wd, bd, input, hs_ws);
    ln_kernel<<<NROW, 256, 0, stream>>>(
        hs_ws, ln_g, ln_b, (float*)d_out);
}